// Round 15
// baseline (335.019 us; speedup 1.0000x reference)
//
#include <hip/hip_runtime.h>
#include <hip/hip_bf16.h>
#include <hip/hip_fp16.h>
#include <math.h>

// ---------------------------------------------------------------------------
// 2-layer GAT (PyG GATConv, concat=False, add_self_loops=True) on MI355X.
// R15: hist fused into gemm1 dispatch (independent work, union'd 50KB LDS,
// same occupancy), node_kernel unroll 16/4/1. NB=4 buckets, u16 cnt_priv,
// 512-thread scatter, unified 16B edge record, zero per-edge device atomics.
// ---------------------------------------------------------------------------

#define NS 64         // edge slices
#define NB 4          // node buckets
#define MAXNPB 12500  // max nodes per bucket (N <= 50000)

__device__ __forceinline__ float lrelu(float x) { return x > 0.f ? x : 0.2f * x; }

__device__ __forceinline__ unsigned int fenc(float f) {
    unsigned int u = __float_as_uint(f);
    return (u & 0x80000000u) ? ~u : (u | 0x80000000u);
}
__device__ __forceinline__ float fdec(unsigned int e) {
    unsigned int u = (e & 0x80000000u) ? (e & 0x7FFFFFFFu) : ~e;
    return __uint_as_float(u);
}

__device__ __forceinline__ unsigned short f2bf(float x) {
    unsigned u = __float_as_uint(x);
    return (unsigned short)((u + 0x7FFFu + ((u >> 16) & 1u)) >> 16);
}
__device__ __forceinline__ float bflo(unsigned w) { return __uint_as_float(w << 16); }
__device__ __forceinline__ float bfhi(unsigned w) { return __uint_as_float(w & 0xFFFF0000u); }

__device__ __forceinline__ unsigned pack_h2(float a, float b) {
    const __half2 h = __float22half2_rn(make_float2(a, b));
    return *(const unsigned*)&h;
}
__device__ __forceinline__ float2 unpack_h2(unsigned w) {
    __half2 h = *(const __half2*)&w;
    return __half22float2(h);
}

// ---------------- scan stage 1: slice prefix (in place, u16) + block sums --
__global__ __launch_bounds__(256) void scan_part(unsigned short* __restrict__ cnt_priv,
                                                 int* __restrict__ deg,
                                                 int* __restrict__ bsum, int n) {
    __shared__ int red[256];
    const int t = threadIdx.x;
    const int node = blockIdx.x * 256 + t;
    int run = 0;
    if (node < n) {
#pragma unroll 4
        for (int s = 0; s < NS; ++s) {
            unsigned short* p = &cnt_priv[(size_t)s * n + node];
            const int c = *p;
            *p = (unsigned short)run;   // exclusive prefix over slices
            run += c;
        }
        deg[node] = run;
    }
    red[t] = (node < n) ? run : 0;
    __syncthreads();
    for (int o = 128; o > 0; o >>= 1) {
        if (t < o) red[t] += red[t + o];
        __syncthreads();
    }
    if (t == 0) bsum[blockIdx.x] = red[0];
}

__global__ __launch_bounds__(256) void scan_mid(const int* __restrict__ bsum,
                                                int* __restrict__ boff, int nb,
                                                int* __restrict__ rowptr, int n) {
    __shared__ int s[256];
    const int t = threadIdx.x;
    const int v = (t < nb) ? bsum[t] : 0;
    s[t] = v;
    __syncthreads();
    for (int o = 1; o < 256; o <<= 1) {
        const int u = (t >= o) ? s[t - o] : 0;
        __syncthreads();
        s[t] += u;
        __syncthreads();
    }
    if (t < nb) boff[t] = s[t] - v;   // exclusive block offset
    if (t == 255) rowptr[n] = s[255]; // total
}

__global__ __launch_bounds__(256) void scan_final(const int* __restrict__ deg,
                                                  const int* __restrict__ boff,
                                                  int* __restrict__ rowptr, int n) {
    __shared__ int s[256];
    const int t = threadIdx.x;
    const int i = blockIdx.x * 256 + t;
    const int v = (i < n) ? deg[i] : 0;
    s[t] = v;
    __syncthreads();
    for (int o = 1; o < 256; o <<= 1) {
        const int u = (t >= o) ? s[t - o] : 0;
        __syncthreads();
        s[t] += u;
        __syncthreads();
    }
    if (i < n) rowptr[i] = boff[blockIdx.x] + s[t] - v;
}

// ---------------- scatter + layer-1 edge weights (fused) -------------------
// LDS cursor seeded from rowptr+cnt_priv (no device atomics). Record:
// esd[p] = { src*16, dst*16, half2(q_pos0,q_pos1), half2(q_pos2,q_pos3) }.
__global__ __launch_bounds__(512) void scatter_kernel(
    const int* __restrict__ src, const int* __restrict__ dst,
    const int* __restrict__ rowptr, const unsigned short* __restrict__ cnt_priv,
    const float* __restrict__ asrc, const float* __restrict__ adst,
    const unsigned int* __restrict__ gmax,
    uint4* __restrict__ esd, int E, int n, int npb) {
    __shared__ int cur[MAXNPB];
    const int b = blockIdx.x & (NB - 1);
    const int s = blockIdx.x / NB;
    const int lo = b * npb;
    const int hi = min(lo + npb, n);
    const int span = hi - lo;
    if (span <= 0) return;
    {
        const unsigned short* cp = cnt_priv + (size_t)s * n + lo;
        const int* rp = rowptr + lo;
        for (int j = threadIdx.x; j < span; j += 512) cur[j] = rp[j] + (int)cp[j];
    }
    __syncthreads();
    const char* aB = (const char*)asrc;
    const char* dB = (const char*)adst;
    const float g0 = fdec(gmax[0]), g1 = fdec(gmax[1]);
    const float g2 = fdec(gmax[2]), g3 = fdec(gmax[3]);

    auto place = [&](int sv, int dv) {
        const int p = atomicAdd(&cur[dv - lo], 1);
        const unsigned s16 = (unsigned)(sv << 4);
        const unsigned d16 = (unsigned)(dv << 4);
        const float4 as = *(const float4*)(aB + s16);
        const float4 ad = *(const float4*)(dB + d16);
        const float q0 = __expf(lrelu(as.x + ad.x) - lrelu(g0 + ad.x));
        const float q1 = __expf(lrelu(as.y + ad.y) - lrelu(g1 + ad.y));
        const float q2 = __expf(lrelu(as.z + ad.z) - lrelu(g2 + ad.z));
        const float q3 = __expf(lrelu(as.w + ad.w) - lrelu(g3 + ad.w));
        esd[p] = make_uint4(s16, d16, pack_h2(q0, q1), pack_h2(q2, q3));
    };

    const int E4 = E >> 2;
    const int len4 = (E4 + NS - 1) / NS;
    const int beg4 = s * len4;
    const int end4 = min(beg4 + len4, E4);
    const int4* dst4 = (const int4*)dst;
    const int4* src4 = (const int4*)src;
    for (int i = beg4 + threadIdx.x; i < end4; i += 512) {
        const int4 d = dst4[i];
        const int4 sv = src4[i];
        if (d.x >= lo && d.x < hi) place(sv.x, d.x);
        if (d.y >= lo && d.y < hi) place(sv.y, d.y);
        if (d.z >= lo && d.z < hi) place(sv.z, d.z);
        if (d.w >= lo && d.w < hi) place(sv.w, d.w);
    }
    if (s == NS - 1) {
        for (int i = (E4 << 2) + threadIdx.x; i < E; i += 512) {
            const int d = dst[i];
            if (d >= lo && d < hi) place(src[i], d);
        }
    }
}

// ---------------- layer-2 edge weights (rewrite q half of esd) -------------
__global__ __launch_bounds__(256) void edge_w_kernel(
    uint4* __restrict__ esd,
    const float* __restrict__ asrc, const float* __restrict__ adst,
    const unsigned int* __restrict__ gmax, int Etot) {
    const char* aB = (const char*)asrc;
    const char* dB = (const char*)adst;
    const float g0 = fdec(gmax[0]), g1 = fdec(gmax[1]);
    const float g2 = fdec(gmax[2]), g3 = fdec(gmax[3]);
    for (int i = blockIdx.x * blockDim.x + threadIdx.x; i < Etot;
         i += gridDim.x * blockDim.x) {
        const unsigned long long sd =
            __builtin_nontemporal_load((const unsigned long long*)&esd[i]);
        const unsigned s16 = (unsigned)sd;
        const unsigned d16 = (unsigned)(sd >> 32);
        const float4 as = *(const float4*)(aB + s16);
        const float4 ad = *(const float4*)(dB + d16);
        const float q0 = __expf(lrelu(as.x + ad.x) - lrelu(g0 + ad.x));
        const float q1 = __expf(lrelu(as.y + ad.y) - lrelu(g1 + ad.y));
        const float q2 = __expf(lrelu(as.z + ad.z) - lrelu(g2 + ad.z));
        const float q3 = __expf(lrelu(as.w + ad.w) - lrelu(g3 + ad.w));
        const unsigned long long rec =
            ((unsigned long long)pack_h2(q2, q3) << 32) | pack_h2(q0, q1);
        __builtin_nontemporal_store(
            rec, (unsigned long long*)((char*)&esd[i] + 8));
    }
}

// ---------------- GEMM + alpha + gmax (+ fused LDS hist, K=128 only) -------
// 64 rows/block, acc[8][4]; k unrolled x4. Union'd LDS: gemm carves Ws+Xs,
// hist blocks (blockIdx >= gemmGrid, layer 1 only) carve int h[MAXNPB].
// Hb layout (bf16): row*256 + f*8 + hp*4 -> dword = (head hp | head hp+2<<16).
template <int K>
__global__ __launch_bounds__(256) void gemm_hist(
    const float* __restrict__ X, const float* __restrict__ W,
    const float* __restrict__ AttS, const float* __restrict__ AttD,
    unsigned short* __restrict__ Hb, float* __restrict__ asrc, float* __restrict__ adst,
    unsigned int* __restrict__ gmax, int n, int gemmGrid,
    const int* __restrict__ dst, unsigned short* __restrict__ cnt_priv,
    int E, int npb) {
    constexpr int KC = 32;
    constexpr int GEMM_BYTES = KC * 128 * 4 + 64 * K * 4;
    constexpr int HIST_BYTES = (K == 128) ? (MAXNPB * 4) : 0;
    constexpr int SMEM_BYTES = (GEMM_BYTES > HIST_BYTES) ? GEMM_BYTES : HIST_BYTES;
    __shared__ __align__(16) char smem[SMEM_BYTES];
    __shared__ unsigned int smax[4];
    const int tid = threadIdx.x;

    if constexpr (K == 128) {
        if (blockIdx.x >= gemmGrid) {
            // ---- hist role (bucket x slice, LDS-private) ----
            int* h = (int*)smem;
            const int hb = blockIdx.x - gemmGrid;
            const int b = hb & (NB - 1);
            const int s = hb / NB;
            const int lo = b * npb;
            const int hi = min(lo + npb, n);
            const int span = hi - lo;
            if (span <= 0) return;
            for (int j = tid; j < span; j += 256) h[j] = 0;
            __syncthreads();
            const int E4 = E >> 2;
            const int len4 = (E4 + NS - 1) / NS;
            const int beg4 = s * len4;
            const int end4 = min(beg4 + len4, E4);
            const int4* dst4 = (const int4*)dst;
            for (int i = beg4 + tid; i < end4; i += 256) {
                const int4 d = dst4[i];
                if (d.x >= lo && d.x < hi) atomicAdd(&h[d.x - lo], 1);
                if (d.y >= lo && d.y < hi) atomicAdd(&h[d.y - lo], 1);
                if (d.z >= lo && d.z < hi) atomicAdd(&h[d.z - lo], 1);
                if (d.w >= lo && d.w < hi) atomicAdd(&h[d.w - lo], 1);
            }
            if (s == NS - 1) {
                for (int i = (E4 << 2) + tid; i < E; i += 256) {
                    const int d = dst[i];
                    if (d >= lo && d < hi) atomicAdd(&h[d - lo], 1);
                }
            }
            __syncthreads();
            unsigned short* outp = cnt_priv + (size_t)s * n + lo;
            for (int j = tid; j < span; j += 256) outp[j] = (unsigned short)h[j];
            return;
        }
    }

    // ---- gemm role ----
    float* Ws = (float*)smem;
    float* Xs = (float*)(smem + KC * 128 * 4);
    const int r = tid >> 5;          // row-in-batch 0..7
    const int sub = tid & 31;
    const int head = sub >> 3;       // 0..3
    const int pos = ((head & 1) << 1) | (head >> 1);  // [0,2,1,3] order
    const int fc = (sub & 7) * 4;    // feat-in-head base
    const int rowBase = blockIdx.x * 64;

    if (tid < 4) smax[tid] = 0u;
    {
        const float4* X4 = (const float4*)X;
        float4* Xs4 = (float4*)Xs;
        const int K4 = K / 4;
        for (int i = tid; i < 64 * K4; i += 256) {
            int rr = rowBase + i / K4;
            Xs4[i] = (rr < n) ? X4[(size_t)rr * K4 + (i % K4)] : make_float4(0.f, 0.f, 0.f, 0.f);
        }
    }

    float acc[8][4] = {};
    const float4* Ws4 = (const float4*)Ws;
    for (int kt = 0; kt < K; kt += KC) {
        __syncthreads();
        {
            const float4* W4 = (const float4*)(W + kt * 128);
            float4* WsS = (float4*)Ws;
#pragma unroll
            for (int i = 0; i < 4; ++i) WsS[tid + i * 256] = W4[tid + i * 256];
        }
        __syncthreads();
#pragma unroll
        for (int k = 0; k < KC; k += 4) {
            float4 wv[4];
#pragma unroll
            for (int j = 0; j < 4; ++j) wv[j] = Ws4[(k + j) * 32 + sub];
            float4 xv[8];
#pragma unroll
            for (int b = 0; b < 8; ++b)
                xv[b] = *(const float4*)&Xs[(b * 8 + r) * K + kt + k];
#pragma unroll
            for (int b = 0; b < 8; ++b) {
                acc[b][0] = fmaf(xv[b].x, wv[0].x, acc[b][0]);
                acc[b][1] = fmaf(xv[b].x, wv[0].y, acc[b][1]);
                acc[b][2] = fmaf(xv[b].x, wv[0].z, acc[b][2]);
                acc[b][3] = fmaf(xv[b].x, wv[0].w, acc[b][3]);
                acc[b][0] = fmaf(xv[b].y, wv[1].x, acc[b][0]);
                acc[b][1] = fmaf(xv[b].y, wv[1].y, acc[b][1]);
                acc[b][2] = fmaf(xv[b].y, wv[1].z, acc[b][2]);
                acc[b][3] = fmaf(xv[b].y, wv[1].w, acc[b][3]);
                acc[b][0] = fmaf(xv[b].z, wv[2].x, acc[b][0]);
                acc[b][1] = fmaf(xv[b].z, wv[2].y, acc[b][1]);
                acc[b][2] = fmaf(xv[b].z, wv[2].z, acc[b][2]);
                acc[b][3] = fmaf(xv[b].z, wv[2].w, acc[b][3]);
                acc[b][0] = fmaf(xv[b].w, wv[3].x, acc[b][0]);
                acc[b][1] = fmaf(xv[b].w, wv[3].y, acc[b][1]);
                acc[b][2] = fmaf(xv[b].w, wv[3].z, acc[b][2]);
                acc[b][3] = fmaf(xv[b].w, wv[3].w, acc[b][3]);
            }
        }
    }

    float a_s[4], a_d[4];
#pragma unroll
    for (int j = 0; j < 4; ++j) {
        a_s[j] = AttS[head * 32 + fc + j];
        a_d[j] = AttD[head * 32 + fc + j];
    }
#pragma unroll
    for (int b = 0; b < 8; ++b) {
        const int row = rowBase + b * 8 + r;
        const float p0 = __shfl_xor(acc[b][0], 16);  // partner head^2, same feats
        const float p1 = __shfl_xor(acc[b][1], 16);
        const float p2 = __shfl_xor(acc[b][2], 16);
        const float p3 = __shfl_xor(acc[b][3], 16);
        if (row < n) {
            if (head < 2) {
                char* base = (char*)Hb + (size_t)row * 256 + (unsigned)fc * 8 + head * 4;
                *(unsigned*)(base + 0)  = (unsigned)f2bf(acc[b][0]) | ((unsigned)f2bf(p0) << 16);
                *(unsigned*)(base + 8)  = (unsigned)f2bf(acc[b][1]) | ((unsigned)f2bf(p1) << 16);
                *(unsigned*)(base + 16) = (unsigned)f2bf(acc[b][2]) | ((unsigned)f2bf(p2) << 16);
                *(unsigned*)(base + 24) = (unsigned)f2bf(acc[b][3]) | ((unsigned)f2bf(p3) << 16);
            }
            float ps = acc[b][0] * a_s[0] + acc[b][1] * a_s[1] +
                       acc[b][2] * a_s[2] + acc[b][3] * a_s[3];
            float pd = acc[b][0] * a_d[0] + acc[b][1] * a_d[1] +
                       acc[b][2] * a_d[2] + acc[b][3] * a_d[3];
#pragma unroll
            for (int msk = 1; msk < 8; msk <<= 1) {
                ps += __shfl_xor(ps, msk);
                pd += __shfl_xor(pd, msk);
            }
            if ((sub & 7) == 0) {
                asrc[row * 4 + pos] = ps;
                adst[row * 4 + pos] = pd;
                atomicMax(&smax[pos], fenc(ps));
            }
        }
    }
    __syncthreads();
    if (tid < 4) atomicMax(&gmax[tid], smax[tid]);
}

// ---------------- per-node aggregate: 32 lanes/node, 4 heads in-lane -------
// Unroll 16/4/1 for deep gather MLP.
__global__ __launch_bounds__(256) void node_kernel(
    const int* __restrict__ rowptr, const uint4* __restrict__ esd,
    const unsigned short* __restrict__ Hb, const float* __restrict__ asrc,
    const float* __restrict__ adst, const unsigned int* __restrict__ gmax,
    const float* __restrict__ bias,
    float* __restrict__ outp, int n, int apply_elu) {
    const int node = blockIdx.x * 8 + (threadIdx.x >> 5);
    if (node >= n) return;
    const unsigned f = threadIdx.x & 31;
    const unsigned f8 = f * 8;
    const char* hB = (const char*)Hb;
    const unsigned long long* eB = (const unsigned long long*)esd;

    const int beg = rowptr[node], end = rowptr[node + 1];
    const float4 ad4 = *(const float4*)(adst + (size_t)node * 4);  // pos order
    const float4 as4 = *(const float4*)(asrc + (size_t)node * 4);
    const float M0 = lrelu(fdec(gmax[0]) + ad4.x);
    const float M1 = lrelu(fdec(gmax[1]) + ad4.y);
    const float M2 = lrelu(fdec(gmax[2]) + ad4.z);
    const float M3 = lrelu(fdec(gmax[3]) + ad4.w);

    // self loop
    const float q0 = __expf(lrelu(as4.x + ad4.x) - M0);
    const float q1 = __expf(lrelu(as4.y + ad4.y) - M1);
    const float q2 = __expf(lrelu(as4.z + ad4.z) - M2);
    const float q3 = __expf(lrelu(as4.w + ad4.w) - M3);
    float s0 = q0, s1 = q1, s2 = q2, s3 = q3;
    const uint2 hs = *(const uint2*)(hB + ((size_t)node << 8) + f8);
    float a0 = q0 * bflo(hs.x);   // pos0 = head0
    float a1 = q1 * bfhi(hs.x);   // pos1 = head2
    float a2 = q2 * bflo(hs.y);   // pos2 = head1
    float a3 = q3 * bfhi(hs.y);   // pos3 = head3

    int i = beg;
    for (; i + 16 <= end; i += 16) {
        unsigned long long e0[16], e1[16];
#pragma unroll
        for (int u = 0; u < 16; ++u) {
            e0[u] = __builtin_nontemporal_load(&eB[(size_t)(i + u) * 2]);      // {s16,d16}
            e1[u] = __builtin_nontemporal_load(&eB[(size_t)(i + u) * 2 + 1]);  // {q01,q23}
        }
        uint2 h[16];
#pragma unroll
        for (int u = 0; u < 16; ++u)
            h[u] = *(const uint2*)(hB + (((unsigned)e0[u]) << 4) + f8);
#pragma unroll
        for (int u = 0; u < 16; ++u) {
            const float2 qa = unpack_h2((unsigned)e1[u]);
            const float2 qb = unpack_h2((unsigned)(e1[u] >> 32));
            s0 += qa.x; s1 += qa.y; s2 += qb.x; s3 += qb.y;
            a0 = fmaf(qa.x, bflo(h[u].x), a0);
            a1 = fmaf(qa.y, bfhi(h[u].x), a1);
            a2 = fmaf(qb.x, bflo(h[u].y), a2);
            a3 = fmaf(qb.y, bfhi(h[u].y), a3);
        }
    }
    for (; i + 4 <= end; i += 4) {
        unsigned long long e0[4], e1[4];
#pragma unroll
        for (int u = 0; u < 4; ++u) {
            e0[u] = __builtin_nontemporal_load(&eB[(size_t)(i + u) * 2]);
            e1[u] = __builtin_nontemporal_load(&eB[(size_t)(i + u) * 2 + 1]);
        }
        uint2 h[4];
#pragma unroll
        for (int u = 0; u < 4; ++u)
            h[u] = *(const uint2*)(hB + (((unsigned)e0[u]) << 4) + f8);
#pragma unroll
        for (int u = 0; u < 4; ++u) {
            const float2 qa = unpack_h2((unsigned)e1[u]);
            const float2 qb = unpack_h2((unsigned)(e1[u] >> 32));
            s0 += qa.x; s1 += qa.y; s2 += qb.x; s3 += qb.y;
            a0 = fmaf(qa.x, bflo(h[u].x), a0);
            a1 = fmaf(qa.y, bfhi(h[u].x), a1);
            a2 = fmaf(qb.x, bflo(h[u].y), a2);
            a3 = fmaf(qb.y, bfhi(h[u].y), a3);
        }
    }
    for (; i < end; ++i) {
        const unsigned long long e0 = __builtin_nontemporal_load(&eB[(size_t)i * 2]);
        const unsigned long long e1 = __builtin_nontemporal_load(&eB[(size_t)i * 2 + 1]);
        const uint2 h = *(const uint2*)(hB + (((unsigned)e0) << 4) + f8);
        const float2 qa = unpack_h2((unsigned)e1);
        const float2 qb = unpack_h2((unsigned)(e1 >> 32));
        s0 += qa.x; s1 += qa.y; s2 += qb.x; s3 += qb.y;
        a0 = fmaf(qa.x, bflo(h.x), a0);
        a1 = fmaf(qa.y, bfhi(h.x), a1);
        a2 = fmaf(qb.x, bflo(h.y), a2);
        a3 = fmaf(qb.y, bfhi(h.y), a3);
    }

    float v = a0 / s0 + a1 / s1 + a2 / s2 + a3 / s3;
    v = v * 0.25f + bias[f];
    if (apply_elu) v = (v > 0.f) ? v : (__expf(v) - 1.f);
    outp[(size_t)node * 32 + f] = v;
}

// ---------------- launch ----------------

extern "C" void kernel_launch(void* const* d_in, const int* in_sizes, int n_in,
                              void* d_out, int out_size, void* d_ws, size_t ws_size,
                              hipStream_t stream) {
    const int N = in_sizes[0] / 128;
    const int E = in_sizes[1] / 2;
    const float* x = (const float*)d_in[0];
    const int* ei = (const int*)d_in[1];
    const float* W1 = (const float*)d_in[2];
    const float* atS1 = (const float*)d_in[3];
    const float* atD1 = (const float*)d_in[4];
    const float* b1 = (const float*)d_in[5];
    const float* W2 = (const float*)d_in[6];
    const float* atS2 = (const float*)d_in[7];
    const float* atD2 = (const float*)d_in[8];
    const float* b2 = (const float*)d_in[9];
    float* out = (float*)d_out;

    char* ws = (char*)d_ws;
    size_t off = 0;
    auto alloc = [&](size_t bytes) {
        void* p = ws + off;
        off = (off + bytes + 255) & ~(size_t)255;
        return p;
    };
    unsigned int* gmax = (unsigned int*)alloc(8 * sizeof(unsigned int)); // [layer][pos]
    unsigned short* cnt_priv = (unsigned short*)alloc((size_t)NS * N * 2);
    int* deg = (int*)alloc((size_t)N * 4);
    int* rowptr = (int*)alloc((size_t)(N + 1) * 4);
    int* bsum = (int*)alloc(256 * 4);
    int* boff = (int*)alloc(256 * 4);
    uint4* esd = (uint4*)alloc((size_t)E * 16);
    unsigned short* hb = (unsigned short*)alloc((size_t)N * 128 * 2);  // packed bf16
    float* av_s = (float*)alloc((size_t)N * 4 * 4);
    float* av_d = (float*)alloc((size_t)N * 4 * 4);
    float* x2 = (float*)alloc((size_t)N * 32 * 4);

    const int* e_src = ei;
    const int* e_dst = ei + E;

    const int gemmGrid = (N + 63) / 64;
    const int nodeGrid = (N + 7) / 8;
    const int npb = (N + NB - 1) / NB;       // nodes per bucket (<= MAXNPB)
    const int scanGrid = (N + 255) / 256;    // must be <= 256
    const int bsGrid = NB * NS;              // bucket x slice blocks

    (void)hipMemsetAsync(gmax, 0, 8 * sizeof(unsigned int), stream);

    // layer-1 GEMM + hist fused (independent work, one dispatch)
    gemm_hist<128><<<gemmGrid + bsGrid, 256, 0, stream>>>(
        x, W1, atS1, atD1, hb, av_s, av_d, gmax, N, gemmGrid,
        e_dst, cnt_priv, E, npb);
    scan_part<<<scanGrid, 256, 0, stream>>>(cnt_priv, deg, bsum, N);
    scan_mid<<<1, 256, 0, stream>>>(bsum, boff, scanGrid, rowptr, N);
    scan_final<<<scanGrid, 256, 0, stream>>>(deg, boff, rowptr, N);
    scatter_kernel<<<bsGrid, 512, 0, stream>>>(
        e_src, e_dst, rowptr, cnt_priv, av_s, av_d, gmax, esd, E, N, npb);
    node_kernel<<<nodeGrid, 256, 0, stream>>>(rowptr, esd, hb, av_s, av_d, gmax,
                                              b1, x2, N, 1);
    // layer 2
    gemm_hist<32><<<gemmGrid, 256, 0, stream>>>(
        x2, W2, atS2, atD2, hb, av_s, av_d, gmax + 4, N, gemmGrid,
        nullptr, nullptr, 0, 0);
    edge_w_kernel<<<2048, 256, 0, stream>>>(esd, av_s, av_d, gmax + 4, E);
    node_kernel<<<nodeGrid, 256, 0, stream>>>(rowptr, esd, hb, av_s, av_d, gmax + 4,
                                              b2, out, N, 0);
}

// Round 16
// 325.653 us; speedup vs baseline: 1.0288x; 1.0288x over previous
//
#include <hip/hip_runtime.h>
#include <hip/hip_bf16.h>
#include <hip/hip_fp16.h>
#include <math.h>

// ---------------------------------------------------------------------------
// 2-layer GAT (PyG GATConv, concat=False, add_self_loops=True) on MI355X.
// R16: node_kernel back to unroll 8 (R15's unroll-16 cost occupancy 61->35%),
// single 16B uint4 record load per edge (was 2x u64). Hist stays fused into
// gemm1 dispatch. NB=4, u16 cnt_priv, 512-thread scatter, zero edge atomics.
// ---------------------------------------------------------------------------

#define NS 64         // edge slices
#define NB 4          // node buckets
#define MAXNPB 12500  // max nodes per bucket (N <= 50000)

typedef unsigned int u32x4 __attribute__((ext_vector_type(4)));

__device__ __forceinline__ float lrelu(float x) { return x > 0.f ? x : 0.2f * x; }

__device__ __forceinline__ unsigned int fenc(float f) {
    unsigned int u = __float_as_uint(f);
    return (u & 0x80000000u) ? ~u : (u | 0x80000000u);
}
__device__ __forceinline__ float fdec(unsigned int e) {
    unsigned int u = (e & 0x80000000u) ? (e & 0x7FFFFFFFu) : ~e;
    return __uint_as_float(u);
}

__device__ __forceinline__ unsigned short f2bf(float x) {
    unsigned u = __float_as_uint(x);
    return (unsigned short)((u + 0x7FFFu + ((u >> 16) & 1u)) >> 16);
}
__device__ __forceinline__ float bflo(unsigned w) { return __uint_as_float(w << 16); }
__device__ __forceinline__ float bfhi(unsigned w) { return __uint_as_float(w & 0xFFFF0000u); }

__device__ __forceinline__ unsigned pack_h2(float a, float b) {
    const __half2 h = __float22half2_rn(make_float2(a, b));
    return *(const unsigned*)&h;
}
__device__ __forceinline__ float2 unpack_h2(unsigned w) {
    __half2 h = *(const __half2*)&w;
    return __half22float2(h);
}

// ---------------- scan stage 1: slice prefix (in place, u16) + block sums --
__global__ __launch_bounds__(256) void scan_part(unsigned short* __restrict__ cnt_priv,
                                                 int* __restrict__ deg,
                                                 int* __restrict__ bsum, int n) {
    __shared__ int red[256];
    const int t = threadIdx.x;
    const int node = blockIdx.x * 256 + t;
    int run = 0;
    if (node < n) {
#pragma unroll 4
        for (int s = 0; s < NS; ++s) {
            unsigned short* p = &cnt_priv[(size_t)s * n + node];
            const int c = *p;
            *p = (unsigned short)run;   // exclusive prefix over slices
            run += c;
        }
        deg[node] = run;
    }
    red[t] = (node < n) ? run : 0;
    __syncthreads();
    for (int o = 128; o > 0; o >>= 1) {
        if (t < o) red[t] += red[t + o];
        __syncthreads();
    }
    if (t == 0) bsum[blockIdx.x] = red[0];
}

__global__ __launch_bounds__(256) void scan_mid(const int* __restrict__ bsum,
                                                int* __restrict__ boff, int nb,
                                                int* __restrict__ rowptr, int n) {
    __shared__ int s[256];
    const int t = threadIdx.x;
    const int v = (t < nb) ? bsum[t] : 0;
    s[t] = v;
    __syncthreads();
    for (int o = 1; o < 256; o <<= 1) {
        const int u = (t >= o) ? s[t - o] : 0;
        __syncthreads();
        s[t] += u;
        __syncthreads();
    }
    if (t < nb) boff[t] = s[t] - v;   // exclusive block offset
    if (t == 255) rowptr[n] = s[255]; // total
}

__global__ __launch_bounds__(256) void scan_final(const int* __restrict__ deg,
                                                  const int* __restrict__ boff,
                                                  int* __restrict__ rowptr, int n) {
    __shared__ int s[256];
    const int t = threadIdx.x;
    const int i = blockIdx.x * 256 + t;
    const int v = (i < n) ? deg[i] : 0;
    s[t] = v;
    __syncthreads();
    for (int o = 1; o < 256; o <<= 1) {
        const int u = (t >= o) ? s[t - o] : 0;
        __syncthreads();
        s[t] += u;
        __syncthreads();
    }
    if (i < n) rowptr[i] = boff[blockIdx.x] + s[t] - v;
}

// ---------------- scatter + layer-1 edge weights (fused) -------------------
// LDS cursor seeded from rowptr+cnt_priv (no device atomics). Record:
// esd[p] = { src*16, dst*16, half2(q_pos0,q_pos1), half2(q_pos2,q_pos3) }.
__global__ __launch_bounds__(512) void scatter_kernel(
    const int* __restrict__ src, const int* __restrict__ dst,
    const int* __restrict__ rowptr, const unsigned short* __restrict__ cnt_priv,
    const float* __restrict__ asrc, const float* __restrict__ adst,
    const unsigned int* __restrict__ gmax,
    uint4* __restrict__ esd, int E, int n, int npb) {
    __shared__ int cur[MAXNPB];
    const int b = blockIdx.x & (NB - 1);
    const int s = blockIdx.x / NB;
    const int lo = b * npb;
    const int hi = min(lo + npb, n);
    const int span = hi - lo;
    if (span <= 0) return;
    {
        const unsigned short* cp = cnt_priv + (size_t)s * n + lo;
        const int* rp = rowptr + lo;
        for (int j = threadIdx.x; j < span; j += 512) cur[j] = rp[j] + (int)cp[j];
    }
    __syncthreads();
    const char* aB = (const char*)asrc;
    const char* dB = (const char*)adst;
    const float g0 = fdec(gmax[0]), g1 = fdec(gmax[1]);
    const float g2 = fdec(gmax[2]), g3 = fdec(gmax[3]);

    auto place = [&](int sv, int dv) {
        const int p = atomicAdd(&cur[dv - lo], 1);
        const unsigned s16 = (unsigned)(sv << 4);
        const unsigned d16 = (unsigned)(dv << 4);
        const float4 as = *(const float4*)(aB + s16);
        const float4 ad = *(const float4*)(dB + d16);
        const float q0 = __expf(lrelu(as.x + ad.x) - lrelu(g0 + ad.x));
        const float q1 = __expf(lrelu(as.y + ad.y) - lrelu(g1 + ad.y));
        const float q2 = __expf(lrelu(as.z + ad.z) - lrelu(g2 + ad.z));
        const float q3 = __expf(lrelu(as.w + ad.w) - lrelu(g3 + ad.w));
        esd[p] = make_uint4(s16, d16, pack_h2(q0, q1), pack_h2(q2, q3));
    };

    const int E4 = E >> 2;
    const int len4 = (E4 + NS - 1) / NS;
    const int beg4 = s * len4;
    const int end4 = min(beg4 + len4, E4);
    const int4* dst4 = (const int4*)dst;
    const int4* src4 = (const int4*)src;
    for (int i = beg4 + threadIdx.x; i < end4; i += 512) {
        const int4 d = dst4[i];
        const int4 sv = src4[i];
        if (d.x >= lo && d.x < hi) place(sv.x, d.x);
        if (d.y >= lo && d.y < hi) place(sv.y, d.y);
        if (d.z >= lo && d.z < hi) place(sv.z, d.z);
        if (d.w >= lo && d.w < hi) place(sv.w, d.w);
    }
    if (s == NS - 1) {
        for (int i = (E4 << 2) + threadIdx.x; i < E; i += 512) {
            const int d = dst[i];
            if (d >= lo && d < hi) place(src[i], d);
        }
    }
}

// ---------------- layer-2 edge weights (rewrite q half of esd) -------------
__global__ __launch_bounds__(256) void edge_w_kernel(
    uint4* __restrict__ esd,
    const float* __restrict__ asrc, const float* __restrict__ adst,
    const unsigned int* __restrict__ gmax, int Etot) {
    const char* aB = (const char*)asrc;
    const char* dB = (const char*)adst;
    const float g0 = fdec(gmax[0]), g1 = fdec(gmax[1]);
    const float g2 = fdec(gmax[2]), g3 = fdec(gmax[3]);
    for (int i = blockIdx.x * blockDim.x + threadIdx.x; i < Etot;
         i += gridDim.x * blockDim.x) {
        const unsigned long long sd =
            __builtin_nontemporal_load((const unsigned long long*)&esd[i]);
        const unsigned s16 = (unsigned)sd;
        const unsigned d16 = (unsigned)(sd >> 32);
        const float4 as = *(const float4*)(aB + s16);
        const float4 ad = *(const float4*)(dB + d16);
        const float q0 = __expf(lrelu(as.x + ad.x) - lrelu(g0 + ad.x));
        const float q1 = __expf(lrelu(as.y + ad.y) - lrelu(g1 + ad.y));
        const float q2 = __expf(lrelu(as.z + ad.z) - lrelu(g2 + ad.z));
        const float q3 = __expf(lrelu(as.w + ad.w) - lrelu(g3 + ad.w));
        const unsigned long long rec =
            ((unsigned long long)pack_h2(q2, q3) << 32) | pack_h2(q0, q1);
        __builtin_nontemporal_store(
            rec, (unsigned long long*)((char*)&esd[i] + 8));
    }
}

// ---------------- GEMM + alpha + gmax (+ fused LDS hist, K=128 only) -------
// 64 rows/block, acc[8][4]; k unrolled x4. Union'd LDS: gemm carves Ws+Xs,
// hist blocks (blockIdx >= gemmGrid, layer 1 only) carve int h[MAXNPB].
// Hb layout (bf16): row*256 + f*8 + hp*4 -> dword = (head hp | head hp+2<<16).
template <int K>
__global__ __launch_bounds__(256) void gemm_hist(
    const float* __restrict__ X, const float* __restrict__ W,
    const float* __restrict__ AttS, const float* __restrict__ AttD,
    unsigned short* __restrict__ Hb, float* __restrict__ asrc, float* __restrict__ adst,
    unsigned int* __restrict__ gmax, int n, int gemmGrid,
    const int* __restrict__ dst, unsigned short* __restrict__ cnt_priv,
    int E, int npb) {
    constexpr int KC = 32;
    constexpr int GEMM_BYTES = KC * 128 * 4 + 64 * K * 4;
    constexpr int HIST_BYTES = (K == 128) ? (MAXNPB * 4) : 0;
    constexpr int SMEM_BYTES = (GEMM_BYTES > HIST_BYTES) ? GEMM_BYTES : HIST_BYTES;
    __shared__ __align__(16) char smem[SMEM_BYTES];
    __shared__ unsigned int smax[4];
    const int tid = threadIdx.x;

    if constexpr (K == 128) {
        if (blockIdx.x >= gemmGrid) {
            // ---- hist role (bucket x slice, LDS-private) ----
            int* h = (int*)smem;
            const int hb = blockIdx.x - gemmGrid;
            const int b = hb & (NB - 1);
            const int s = hb / NB;
            const int lo = b * npb;
            const int hi = min(lo + npb, n);
            const int span = hi - lo;
            if (span <= 0) return;
            for (int j = tid; j < span; j += 256) h[j] = 0;
            __syncthreads();
            const int E4 = E >> 2;
            const int len4 = (E4 + NS - 1) / NS;
            const int beg4 = s * len4;
            const int end4 = min(beg4 + len4, E4);
            const int4* dst4 = (const int4*)dst;
            for (int i = beg4 + tid; i < end4; i += 256) {
                const int4 d = dst4[i];
                if (d.x >= lo && d.x < hi) atomicAdd(&h[d.x - lo], 1);
                if (d.y >= lo && d.y < hi) atomicAdd(&h[d.y - lo], 1);
                if (d.z >= lo && d.z < hi) atomicAdd(&h[d.z - lo], 1);
                if (d.w >= lo && d.w < hi) atomicAdd(&h[d.w - lo], 1);
            }
            if (s == NS - 1) {
                for (int i = (E4 << 2) + tid; i < E; i += 256) {
                    const int d = dst[i];
                    if (d >= lo && d < hi) atomicAdd(&h[d - lo], 1);
                }
            }
            __syncthreads();
            unsigned short* outp = cnt_priv + (size_t)s * n + lo;
            for (int j = tid; j < span; j += 256) outp[j] = (unsigned short)h[j];
            return;
        }
    }

    // ---- gemm role ----
    float* Ws = (float*)smem;
    float* Xs = (float*)(smem + KC * 128 * 4);
    const int r = tid >> 5;          // row-in-batch 0..7
    const int sub = tid & 31;
    const int head = sub >> 3;       // 0..3
    const int pos = ((head & 1) << 1) | (head >> 1);  // [0,2,1,3] order
    const int fc = (sub & 7) * 4;    // feat-in-head base
    const int rowBase = blockIdx.x * 64;

    if (tid < 4) smax[tid] = 0u;
    {
        const float4* X4 = (const float4*)X;
        float4* Xs4 = (float4*)Xs;
        const int K4 = K / 4;
        for (int i = tid; i < 64 * K4; i += 256) {
            int rr = rowBase + i / K4;
            Xs4[i] = (rr < n) ? X4[(size_t)rr * K4 + (i % K4)] : make_float4(0.f, 0.f, 0.f, 0.f);
        }
    }

    float acc[8][4] = {};
    const float4* Ws4 = (const float4*)Ws;
    for (int kt = 0; kt < K; kt += KC) {
        __syncthreads();
        {
            const float4* W4 = (const float4*)(W + kt * 128);
            float4* WsS = (float4*)Ws;
#pragma unroll
            for (int i = 0; i < 4; ++i) WsS[tid + i * 256] = W4[tid + i * 256];
        }
        __syncthreads();
#pragma unroll
        for (int k = 0; k < KC; k += 4) {
            float4 wv[4];
#pragma unroll
            for (int j = 0; j < 4; ++j) wv[j] = Ws4[(k + j) * 32 + sub];
            float4 xv[8];
#pragma unroll
            for (int b = 0; b < 8; ++b)
                xv[b] = *(const float4*)&Xs[(b * 8 + r) * K + kt + k];
#pragma unroll
            for (int b = 0; b < 8; ++b) {
                acc[b][0] = fmaf(xv[b].x, wv[0].x, acc[b][0]);
                acc[b][1] = fmaf(xv[b].x, wv[0].y, acc[b][1]);
                acc[b][2] = fmaf(xv[b].x, wv[0].z, acc[b][2]);
                acc[b][3] = fmaf(xv[b].x, wv[0].w, acc[b][3]);
                acc[b][0] = fmaf(xv[b].y, wv[1].x, acc[b][0]);
                acc[b][1] = fmaf(xv[b].y, wv[1].y, acc[b][1]);
                acc[b][2] = fmaf(xv[b].y, wv[1].z, acc[b][2]);
                acc[b][3] = fmaf(xv[b].y, wv[1].w, acc[b][3]);
                acc[b][0] = fmaf(xv[b].z, wv[2].x, acc[b][0]);
                acc[b][1] = fmaf(xv[b].z, wv[2].y, acc[b][1]);
                acc[b][2] = fmaf(xv[b].z, wv[2].z, acc[b][2]);
                acc[b][3] = fmaf(xv[b].z, wv[2].w, acc[b][3]);
                acc[b][0] = fmaf(xv[b].w, wv[3].x, acc[b][0]);
                acc[b][1] = fmaf(xv[b].w, wv[3].y, acc[b][1]);
                acc[b][2] = fmaf(xv[b].w, wv[3].z, acc[b][2]);
                acc[b][3] = fmaf(xv[b].w, wv[3].w, acc[b][3]);
            }
        }
    }

    float a_s[4], a_d[4];
#pragma unroll
    for (int j = 0; j < 4; ++j) {
        a_s[j] = AttS[head * 32 + fc + j];
        a_d[j] = AttD[head * 32 + fc + j];
    }
#pragma unroll
    for (int b = 0; b < 8; ++b) {
        const int row = rowBase + b * 8 + r;
        const float p0 = __shfl_xor(acc[b][0], 16);  // partner head^2, same feats
        const float p1 = __shfl_xor(acc[b][1], 16);
        const float p2 = __shfl_xor(acc[b][2], 16);
        const float p3 = __shfl_xor(acc[b][3], 16);
        if (row < n) {
            if (head < 2) {
                char* base = (char*)Hb + (size_t)row * 256 + (unsigned)fc * 8 + head * 4;
                *(unsigned*)(base + 0)  = (unsigned)f2bf(acc[b][0]) | ((unsigned)f2bf(p0) << 16);
                *(unsigned*)(base + 8)  = (unsigned)f2bf(acc[b][1]) | ((unsigned)f2bf(p1) << 16);
                *(unsigned*)(base + 16) = (unsigned)f2bf(acc[b][2]) | ((unsigned)f2bf(p2) << 16);
                *(unsigned*)(base + 24) = (unsigned)f2bf(acc[b][3]) | ((unsigned)f2bf(p3) << 16);
            }
            float ps = acc[b][0] * a_s[0] + acc[b][1] * a_s[1] +
                       acc[b][2] * a_s[2] + acc[b][3] * a_s[3];
            float pd = acc[b][0] * a_d[0] + acc[b][1] * a_d[1] +
                       acc[b][2] * a_d[2] + acc[b][3] * a_d[3];
#pragma unroll
            for (int msk = 1; msk < 8; msk <<= 1) {
                ps += __shfl_xor(ps, msk);
                pd += __shfl_xor(pd, msk);
            }
            if ((sub & 7) == 0) {
                asrc[row * 4 + pos] = ps;
                adst[row * 4 + pos] = pd;
                atomicMax(&smax[pos], fenc(ps));
            }
        }
    }
    __syncthreads();
    if (tid < 4) atomicMax(&gmax[tid], smax[tid]);
}

// ---------------- per-node aggregate: 32 lanes/node, 4 heads in-lane -------
// One 16B uint4 record load per edge + one u64 Hb gather; unroll 8.
__global__ __launch_bounds__(256) void node_kernel(
    const int* __restrict__ rowptr, const uint4* __restrict__ esd,
    const unsigned short* __restrict__ Hb, const float* __restrict__ asrc,
    const float* __restrict__ adst, const unsigned int* __restrict__ gmax,
    const float* __restrict__ bias,
    float* __restrict__ outp, int n, int apply_elu) {
    const int node = blockIdx.x * 8 + (threadIdx.x >> 5);
    if (node >= n) return;
    const unsigned f = threadIdx.x & 31;
    const unsigned f8 = f * 8;
    const char* hB = (const char*)Hb;
    const u32x4* eB = (const u32x4*)esd;

    const int beg = rowptr[node], end = rowptr[node + 1];
    const float4 ad4 = *(const float4*)(adst + (size_t)node * 4);  // pos order
    const float4 as4 = *(const float4*)(asrc + (size_t)node * 4);
    const float M0 = lrelu(fdec(gmax[0]) + ad4.x);
    const float M1 = lrelu(fdec(gmax[1]) + ad4.y);
    const float M2 = lrelu(fdec(gmax[2]) + ad4.z);
    const float M3 = lrelu(fdec(gmax[3]) + ad4.w);

    // self loop
    const float q0 = __expf(lrelu(as4.x + ad4.x) - M0);
    const float q1 = __expf(lrelu(as4.y + ad4.y) - M1);
    const float q2 = __expf(lrelu(as4.z + ad4.z) - M2);
    const float q3 = __expf(lrelu(as4.w + ad4.w) - M3);
    float s0 = q0, s1 = q1, s2 = q2, s3 = q3;
    const uint2 hs = *(const uint2*)(hB + ((size_t)node << 8) + f8);
    float a0 = q0 * bflo(hs.x);   // pos0 = head0
    float a1 = q1 * bfhi(hs.x);   // pos1 = head2
    float a2 = q2 * bflo(hs.y);   // pos2 = head1
    float a3 = q3 * bfhi(hs.y);   // pos3 = head3

    int i = beg;
    for (; i + 8 <= end; i += 8) {
        u32x4 e[8];
#pragma unroll
        for (int u = 0; u < 8; ++u)
            e[u] = __builtin_nontemporal_load(&eB[i + u]);  // {s16,d16,q01,q23}
        uint2 h[8];
#pragma unroll
        for (int u = 0; u < 8; ++u)
            h[u] = *(const uint2*)(hB + (((unsigned)e[u].x) << 4) + f8);
#pragma unroll
        for (int u = 0; u < 8; ++u) {
            const float2 qa = unpack_h2(e[u].z);
            const float2 qb = unpack_h2(e[u].w);
            s0 += qa.x; s1 += qa.y; s2 += qb.x; s3 += qb.y;
            a0 = fmaf(qa.x, bflo(h[u].x), a0);
            a1 = fmaf(qa.y, bfhi(h[u].x), a1);
            a2 = fmaf(qb.x, bflo(h[u].y), a2);
            a3 = fmaf(qb.y, bfhi(h[u].y), a3);
        }
    }
    for (; i < end; ++i) {
        const u32x4 e = __builtin_nontemporal_load(&eB[i]);
        const uint2 h = *(const uint2*)(hB + (((unsigned)e.x) << 4) + f8);
        const float2 qa = unpack_h2(e.z);
        const float2 qb = unpack_h2(e.w);
        s0 += qa.x; s1 += qa.y; s2 += qb.x; s3 += qb.y;
        a0 = fmaf(qa.x, bflo(h.x), a0);
        a1 = fmaf(qa.y, bfhi(h.x), a1);
        a2 = fmaf(qb.x, bflo(h.y), a2);
        a3 = fmaf(qb.y, bfhi(h.y), a3);
    }

    float v = a0 / s0 + a1 / s1 + a2 / s2 + a3 / s3;
    v = v * 0.25f + bias[f];
    if (apply_elu) v = (v > 0.f) ? v : (__expf(v) - 1.f);
    outp[(size_t)node * 32 + f] = v;
}

// ---------------- launch ----------------

extern "C" void kernel_launch(void* const* d_in, const int* in_sizes, int n_in,
                              void* d_out, int out_size, void* d_ws, size_t ws_size,
                              hipStream_t stream) {
    const int N = in_sizes[0] / 128;
    const int E = in_sizes[1] / 2;
    const float* x = (const float*)d_in[0];
    const int* ei = (const int*)d_in[1];
    const float* W1 = (const float*)d_in[2];
    const float* atS1 = (const float*)d_in[3];
    const float* atD1 = (const float*)d_in[4];
    const float* b1 = (const float*)d_in[5];
    const float* W2 = (const float*)d_in[6];
    const float* atS2 = (const float*)d_in[7];
    const float* atD2 = (const float*)d_in[8];
    const float* b2 = (const float*)d_in[9];
    float* out = (float*)d_out;

    char* ws = (char*)d_ws;
    size_t off = 0;
    auto alloc = [&](size_t bytes) {
        void* p = ws + off;
        off = (off + bytes + 255) & ~(size_t)255;
        return p;
    };
    unsigned int* gmax = (unsigned int*)alloc(8 * sizeof(unsigned int)); // [layer][pos]
    unsigned short* cnt_priv = (unsigned short*)alloc((size_t)NS * N * 2);
    int* deg = (int*)alloc((size_t)N * 4);
    int* rowptr = (int*)alloc((size_t)(N + 1) * 4);
    int* bsum = (int*)alloc(256 * 4);
    int* boff = (int*)alloc(256 * 4);
    uint4* esd = (uint4*)alloc((size_t)E * 16);
    unsigned short* hb = (unsigned short*)alloc((size_t)N * 128 * 2);  // packed bf16
    float* av_s = (float*)alloc((size_t)N * 4 * 4);
    float* av_d = (float*)alloc((size_t)N * 4 * 4);
    float* x2 = (float*)alloc((size_t)N * 32 * 4);

    const int* e_src = ei;
    const int* e_dst = ei + E;

    const int gemmGrid = (N + 63) / 64;
    const int nodeGrid = (N + 7) / 8;
    const int npb = (N + NB - 1) / NB;       // nodes per bucket (<= MAXNPB)
    const int scanGrid = (N + 255) / 256;    // must be <= 256
    const int bsGrid = NB * NS;              // bucket x slice blocks

    (void)hipMemsetAsync(gmax, 0, 8 * sizeof(unsigned int), stream);

    // layer-1 GEMM + hist fused (independent work, one dispatch)
    gemm_hist<128><<<gemmGrid + bsGrid, 256, 0, stream>>>(
        x, W1, atS1, atD1, hb, av_s, av_d, gmax, N, gemmGrid,
        e_dst, cnt_priv, E, npb);
    scan_part<<<scanGrid, 256, 0, stream>>>(cnt_priv, deg, bsum, N);
    scan_mid<<<1, 256, 0, stream>>>(bsum, boff, scanGrid, rowptr, N);
    scan_final<<<scanGrid, 256, 0, stream>>>(deg, boff, rowptr, N);
    scatter_kernel<<<bsGrid, 512, 0, stream>>>(
        e_src, e_dst, rowptr, cnt_priv, av_s, av_d, gmax, esd, E, N, npb);
    node_kernel<<<nodeGrid, 256, 0, stream>>>(rowptr, esd, hb, av_s, av_d, gmax,
                                              b1, x2, N, 1);
    // layer 2
    gemm_hist<32><<<gemmGrid, 256, 0, stream>>>(
        x2, W2, atS2, atD2, hb, av_s, av_d, gmax + 4, N, gemmGrid,
        nullptr, nullptr, 0, 0);
    edge_w_kernel<<<2048, 256, 0, stream>>>(esd, av_s, av_d, gmax + 4, E);
    node_kernel<<<nodeGrid, 256, 0, stream>>>(rowptr, esd, hb, av_s, av_d, gmax + 4,
                                              b2, out, N, 0);
}

// Round 17
// 308.545 us; speedup vs baseline: 1.0858x; 1.0554x over previous
//
#include <hip/hip_runtime.h>
#include <hip/hip_bf16.h>
#include <hip/hip_fp16.h>
#include <math.h>

// ---------------------------------------------------------------------------
// 2-layer GAT (PyG GATConv, concat=False, add_self_loops=True) on MI355X.
// R17: GEMM drops Ws LDS staging (W is 64KB, L1/L2-hot -> direct global
// reads); LDS = Xs only (32.8KB) -> 4 blocks/CU + single barrier. Fused hist
// moves to NB_H=8 (25KB) to fit under gemm LDS. Scatter stays NB_S=4.
// Node kernel unchanged (R16: unroll 8, uint4 record, 4 heads in-lane).
// ---------------------------------------------------------------------------

#define NS 64          // edge slices
#define NB_S 4         // scatter node buckets
#define MAXNPB_S 12500 // max nodes per scatter bucket (N <= 50000)
#define NB_H 8         // hist node buckets (fused in gemm1 dispatch)
#define MAXNPB_H 6272  // max nodes per hist bucket (N <= 50176)

typedef unsigned int u32x4 __attribute__((ext_vector_type(4)));

__device__ __forceinline__ float lrelu(float x) { return x > 0.f ? x : 0.2f * x; }

__device__ __forceinline__ unsigned int fenc(float f) {
    unsigned int u = __float_as_uint(f);
    return (u & 0x80000000u) ? ~u : (u | 0x80000000u);
}
__device__ __forceinline__ float fdec(unsigned int e) {
    unsigned int u = (e & 0x80000000u) ? (e & 0x7FFFFFFFu) : ~e;
    return __uint_as_float(u);
}

__device__ __forceinline__ unsigned short f2bf(float x) {
    unsigned u = __float_as_uint(x);
    return (unsigned short)((u + 0x7FFFu + ((u >> 16) & 1u)) >> 16);
}
__device__ __forceinline__ float bflo(unsigned w) { return __uint_as_float(w << 16); }
__device__ __forceinline__ float bfhi(unsigned w) { return __uint_as_float(w & 0xFFFF0000u); }

__device__ __forceinline__ unsigned pack_h2(float a, float b) {
    const __half2 h = __float22half2_rn(make_float2(a, b));
    return *(const unsigned*)&h;
}
__device__ __forceinline__ float2 unpack_h2(unsigned w) {
    __half2 h = *(const __half2*)&w;
    return __half22float2(h);
}

// ---------------- scan stage 1: slice prefix (in place, u16) + block sums --
__global__ __launch_bounds__(256) void scan_part(unsigned short* __restrict__ cnt_priv,
                                                 int* __restrict__ deg,
                                                 int* __restrict__ bsum, int n) {
    __shared__ int red[256];
    const int t = threadIdx.x;
    const int node = blockIdx.x * 256 + t;
    int run = 0;
    if (node < n) {
#pragma unroll 4
        for (int s = 0; s < NS; ++s) {
            unsigned short* p = &cnt_priv[(size_t)s * n + node];
            const int c = *p;
            *p = (unsigned short)run;   // exclusive prefix over slices
            run += c;
        }
        deg[node] = run;
    }
    red[t] = (node < n) ? run : 0;
    __syncthreads();
    for (int o = 128; o > 0; o >>= 1) {
        if (t < o) red[t] += red[t + o];
        __syncthreads();
    }
    if (t == 0) bsum[blockIdx.x] = red[0];
}

__global__ __launch_bounds__(256) void scan_mid(const int* __restrict__ bsum,
                                                int* __restrict__ boff, int nb,
                                                int* __restrict__ rowptr, int n) {
    __shared__ int s[256];
    const int t = threadIdx.x;
    const int v = (t < nb) ? bsum[t] : 0;
    s[t] = v;
    __syncthreads();
    for (int o = 1; o < 256; o <<= 1) {
        const int u = (t >= o) ? s[t - o] : 0;
        __syncthreads();
        s[t] += u;
        __syncthreads();
    }
    if (t < nb) boff[t] = s[t] - v;   // exclusive block offset
    if (t == 255) rowptr[n] = s[255]; // total
}

__global__ __launch_bounds__(256) void scan_final(const int* __restrict__ deg,
                                                  const int* __restrict__ boff,
                                                  int* __restrict__ rowptr, int n) {
    __shared__ int s[256];
    const int t = threadIdx.x;
    const int i = blockIdx.x * 256 + t;
    const int v = (i < n) ? deg[i] : 0;
    s[t] = v;
    __syncthreads();
    for (int o = 1; o < 256; o <<= 1) {
        const int u = (t >= o) ? s[t - o] : 0;
        __syncthreads();
        s[t] += u;
        __syncthreads();
    }
    if (i < n) rowptr[i] = boff[blockIdx.x] + s[t] - v;
}

// ---------------- scatter + layer-1 edge weights (fused) -------------------
// LDS cursor seeded from rowptr+cnt_priv (no device atomics). Record:
// esd[p] = { src*16, dst*16, half2(q_pos0,q_pos1), half2(q_pos2,q_pos3) }.
__global__ __launch_bounds__(512) void scatter_kernel(
    const int* __restrict__ src, const int* __restrict__ dst,
    const int* __restrict__ rowptr, const unsigned short* __restrict__ cnt_priv,
    const float* __restrict__ asrc, const float* __restrict__ adst,
    const unsigned int* __restrict__ gmax,
    uint4* __restrict__ esd, int E, int n, int npb) {
    __shared__ int cur[MAXNPB_S];
    const int b = blockIdx.x & (NB_S - 1);
    const int s = blockIdx.x / NB_S;
    const int lo = b * npb;
    const int hi = min(lo + npb, n);
    const int span = hi - lo;
    if (span <= 0) return;
    {
        const unsigned short* cp = cnt_priv + (size_t)s * n + lo;
        const int* rp = rowptr + lo;
        for (int j = threadIdx.x; j < span; j += 512) cur[j] = rp[j] + (int)cp[j];
    }
    __syncthreads();
    const char* aB = (const char*)asrc;
    const char* dB = (const char*)adst;
    const float g0 = fdec(gmax[0]), g1 = fdec(gmax[1]);
    const float g2 = fdec(gmax[2]), g3 = fdec(gmax[3]);

    auto place = [&](int sv, int dv) {
        const int p = atomicAdd(&cur[dv - lo], 1);
        const unsigned s16 = (unsigned)(sv << 4);
        const unsigned d16 = (unsigned)(dv << 4);
        const float4 as = *(const float4*)(aB + s16);
        const float4 ad = *(const float4*)(dB + d16);
        const float q0 = __expf(lrelu(as.x + ad.x) - lrelu(g0 + ad.x));
        const float q1 = __expf(lrelu(as.y + ad.y) - lrelu(g1 + ad.y));
        const float q2 = __expf(lrelu(as.z + ad.z) - lrelu(g2 + ad.z));
        const float q3 = __expf(lrelu(as.w + ad.w) - lrelu(g3 + ad.w));
        esd[p] = make_uint4(s16, d16, pack_h2(q0, q1), pack_h2(q2, q3));
    };

    const int E4 = E >> 2;
    const int len4 = (E4 + NS - 1) / NS;
    const int beg4 = s * len4;
    const int end4 = min(beg4 + len4, E4);
    const int4* dst4 = (const int4*)dst;
    const int4* src4 = (const int4*)src;
    for (int i = beg4 + threadIdx.x; i < end4; i += 512) {
        const int4 d = dst4[i];
        const int4 sv = src4[i];
        if (d.x >= lo && d.x < hi) place(sv.x, d.x);
        if (d.y >= lo && d.y < hi) place(sv.y, d.y);
        if (d.z >= lo && d.z < hi) place(sv.z, d.z);
        if (d.w >= lo && d.w < hi) place(sv.w, d.w);
    }
    if (s == NS - 1) {
        for (int i = (E4 << 2) + threadIdx.x; i < E; i += 512) {
            const int d = dst[i];
            if (d >= lo && d < hi) place(src[i], d);
        }
    }
}

// ---------------- layer-2 edge weights (rewrite q half of esd) -------------
__global__ __launch_bounds__(256) void edge_w_kernel(
    uint4* __restrict__ esd,
    const float* __restrict__ asrc, const float* __restrict__ adst,
    const unsigned int* __restrict__ gmax, int Etot) {
    const char* aB = (const char*)asrc;
    const char* dB = (const char*)adst;
    const float g0 = fdec(gmax[0]), g1 = fdec(gmax[1]);
    const float g2 = fdec(gmax[2]), g3 = fdec(gmax[3]);
    for (int i = blockIdx.x * blockDim.x + threadIdx.x; i < Etot;
         i += gridDim.x * blockDim.x) {
        const unsigned long long sd =
            __builtin_nontemporal_load((const unsigned long long*)&esd[i]);
        const unsigned s16 = (unsigned)sd;
        const unsigned d16 = (unsigned)(sd >> 32);
        const float4 as = *(const float4*)(aB + s16);
        const float4 ad = *(const float4*)(dB + d16);
        const float q0 = __expf(lrelu(as.x + ad.x) - lrelu(g0 + ad.x));
        const float q1 = __expf(lrelu(as.y + ad.y) - lrelu(g1 + ad.y));
        const float q2 = __expf(lrelu(as.z + ad.z) - lrelu(g2 + ad.z));
        const float q3 = __expf(lrelu(as.w + ad.w) - lrelu(g3 + ad.w));
        const unsigned long long rec =
            ((unsigned long long)pack_h2(q2, q3) << 32) | pack_h2(q0, q1);
        __builtin_nontemporal_store(
            rec, (unsigned long long*)((char*)&esd[i] + 8));
    }
}

// ---------------- GEMM + alpha + gmax (+ fused LDS hist, K=128 only) -------
// 64 rows/block, acc[8][4]; W read DIRECT from global (64KB, L1/L2-hot);
// LDS = Xs only -> one barrier, 4 blocks/CU.
// Hb layout (bf16): row*256 + f*8 + hp*4 -> dword = (head hp | head hp+2<<16).
template <int K>
__global__ __launch_bounds__(256) void gemm_hist(
    const float* __restrict__ X, const float* __restrict__ W,
    const float* __restrict__ AttS, const float* __restrict__ AttD,
    unsigned short* __restrict__ Hb, float* __restrict__ asrc, float* __restrict__ adst,
    unsigned int* __restrict__ gmax, int n, int gemmGrid,
    const int* __restrict__ dst, unsigned short* __restrict__ cnt_priv,
    int E, int npbH) {
    constexpr int GEMM_BYTES = 64 * K * 4;
    constexpr int HIST_BYTES = (K == 128) ? (MAXNPB_H * 4) : 0;
    constexpr int SMEM_BYTES = (GEMM_BYTES > HIST_BYTES) ? GEMM_BYTES : HIST_BYTES;
    __shared__ __align__(16) char smem[SMEM_BYTES];
    __shared__ unsigned int smax[4];
    const int tid = threadIdx.x;

    if constexpr (K == 128) {
        if (blockIdx.x >= gemmGrid) {
            // ---- hist role (bucket x slice, LDS-private, NB_H=8) ----
            int* h = (int*)smem;
            const int hb = blockIdx.x - gemmGrid;
            const int b = hb & (NB_H - 1);
            const int s = hb / NB_H;
            const int lo = b * npbH;
            const int hi = min(lo + npbH, n);
            const int span = hi - lo;
            if (span <= 0) return;
            for (int j = tid; j < span; j += 256) h[j] = 0;
            __syncthreads();
            const int E4 = E >> 2;
            const int len4 = (E4 + NS - 1) / NS;
            const int beg4 = s * len4;
            const int end4 = min(beg4 + len4, E4);
            const int4* dst4 = (const int4*)dst;
            for (int i = beg4 + tid; i < end4; i += 256) {
                const int4 d = dst4[i];
                if (d.x >= lo && d.x < hi) atomicAdd(&h[d.x - lo], 1);
                if (d.y >= lo && d.y < hi) atomicAdd(&h[d.y - lo], 1);
                if (d.z >= lo && d.z < hi) atomicAdd(&h[d.z - lo], 1);
                if (d.w >= lo && d.w < hi) atomicAdd(&h[d.w - lo], 1);
            }
            if (s == NS - 1) {
                for (int i = (E4 << 2) + tid; i < E; i += 256) {
                    const int d = dst[i];
                    if (d >= lo && d < hi) atomicAdd(&h[d - lo], 1);
                }
            }
            __syncthreads();
            unsigned short* outp = cnt_priv + (size_t)s * n + lo;
            for (int j = tid; j < span; j += 256) outp[j] = (unsigned short)h[j];
            return;
        }
    }

    // ---- gemm role ----
    float* Xs = (float*)smem;
    const int r = tid >> 5;          // row-in-batch 0..7
    const int sub = tid & 31;
    const int head = sub >> 3;       // 0..3
    const int pos = ((head & 1) << 1) | (head >> 1);  // [0,2,1,3] order
    const int fc = (sub & 7) * 4;    // feat-in-head base
    const int rowBase = blockIdx.x * 64;

    if (tid < 4) smax[tid] = 0u;
    {
        const float4* X4 = (const float4*)X;
        float4* Xs4 = (float4*)Xs;
        const int K4 = K / 4;
        for (int i = tid; i < 64 * K4; i += 256) {
            int rr = rowBase + i / K4;
            Xs4[i] = (rr < n) ? X4[(size_t)rr * K4 + (i % K4)] : make_float4(0.f, 0.f, 0.f, 0.f);
        }
    }
    __syncthreads();

    float acc[8][4] = {};
    const float4* W4g = (const float4*)W;
#pragma unroll 4
    for (int k = 0; k < K; k += 4) {
        float4 wv[4];
#pragma unroll
        for (int j = 0; j < 4; ++j) wv[j] = W4g[(k + j) * 32 + sub];
        float4 xv[8];
#pragma unroll
        for (int b = 0; b < 8; ++b)
            xv[b] = *(const float4*)&Xs[(b * 8 + r) * K + k];
#pragma unroll
        for (int b = 0; b < 8; ++b) {
            acc[b][0] = fmaf(xv[b].x, wv[0].x, acc[b][0]);
            acc[b][1] = fmaf(xv[b].x, wv[0].y, acc[b][1]);
            acc[b][2] = fmaf(xv[b].x, wv[0].z, acc[b][2]);
            acc[b][3] = fmaf(xv[b].x, wv[0].w, acc[b][3]);
            acc[b][0] = fmaf(xv[b].y, wv[1].x, acc[b][0]);
            acc[b][1] = fmaf(xv[b].y, wv[1].y, acc[b][1]);
            acc[b][2] = fmaf(xv[b].y, wv[1].z, acc[b][2]);
            acc[b][3] = fmaf(xv[b].y, wv[1].w, acc[b][3]);
            acc[b][0] = fmaf(xv[b].z, wv[2].x, acc[b][0]);
            acc[b][1] = fmaf(xv[b].z, wv[2].y, acc[b][1]);
            acc[b][2] = fmaf(xv[b].z, wv[2].z, acc[b][2]);
            acc[b][3] = fmaf(xv[b].z, wv[2].w, acc[b][3]);
            acc[b][0] = fmaf(xv[b].w, wv[3].x, acc[b][0]);
            acc[b][1] = fmaf(xv[b].w, wv[3].y, acc[b][1]);
            acc[b][2] = fmaf(xv[b].w, wv[3].z, acc[b][2]);
            acc[b][3] = fmaf(xv[b].w, wv[3].w, acc[b][3]);
        }
    }

    float a_s[4], a_d[4];
#pragma unroll
    for (int j = 0; j < 4; ++j) {
        a_s[j] = AttS[head * 32 + fc + j];
        a_d[j] = AttD[head * 32 + fc + j];
    }
#pragma unroll
    for (int b = 0; b < 8; ++b) {
        const int row = rowBase + b * 8 + r;
        const float p0 = __shfl_xor(acc[b][0], 16);  // partner head^2, same feats
        const float p1 = __shfl_xor(acc[b][1], 16);
        const float p2 = __shfl_xor(acc[b][2], 16);
        const float p3 = __shfl_xor(acc[b][3], 16);
        if (row < n) {
            if (head < 2) {
                char* base = (char*)Hb + (size_t)row * 256 + (unsigned)fc * 8 + head * 4;
                *(unsigned*)(base + 0)  = (unsigned)f2bf(acc[b][0]) | ((unsigned)f2bf(p0) << 16);
                *(unsigned*)(base + 8)  = (unsigned)f2bf(acc[b][1]) | ((unsigned)f2bf(p1) << 16);
                *(unsigned*)(base + 16) = (unsigned)f2bf(acc[b][2]) | ((unsigned)f2bf(p2) << 16);
                *(unsigned*)(base + 24) = (unsigned)f2bf(acc[b][3]) | ((unsigned)f2bf(p3) << 16);
            }
            float ps = acc[b][0] * a_s[0] + acc[b][1] * a_s[1] +
                       acc[b][2] * a_s[2] + acc[b][3] * a_s[3];
            float pd = acc[b][0] * a_d[0] + acc[b][1] * a_d[1] +
                       acc[b][2] * a_d[2] + acc[b][3] * a_d[3];
#pragma unroll
            for (int msk = 1; msk < 8; msk <<= 1) {
                ps += __shfl_xor(ps, msk);
                pd += __shfl_xor(pd, msk);
            }
            if ((sub & 7) == 0) {
                asrc[row * 4 + pos] = ps;
                adst[row * 4 + pos] = pd;
                atomicMax(&smax[pos], fenc(ps));
            }
        }
    }
    __syncthreads();
    if (tid < 4) atomicMax(&gmax[tid], smax[tid]);
}

// ---------------- per-node aggregate: 32 lanes/node, 4 heads in-lane -------
// One 16B uint4 record load per edge + one u64 Hb gather; unroll 8.
__global__ __launch_bounds__(256) void node_kernel(
    const int* __restrict__ rowptr, const uint4* __restrict__ esd,
    const unsigned short* __restrict__ Hb, const float* __restrict__ asrc,
    const float* __restrict__ adst, const unsigned int* __restrict__ gmax,
    const float* __restrict__ bias,
    float* __restrict__ outp, int n, int apply_elu) {
    const int node = blockIdx.x * 8 + (threadIdx.x >> 5);
    if (node >= n) return;
    const unsigned f = threadIdx.x & 31;
    const unsigned f8 = f * 8;
    const char* hB = (const char*)Hb;
    const u32x4* eB = (const u32x4*)esd;

    const int beg = rowptr[node], end = rowptr[node + 1];
    const float4 ad4 = *(const float4*)(adst + (size_t)node * 4);  // pos order
    const float4 as4 = *(const float4*)(asrc + (size_t)node * 4);
    const float M0 = lrelu(fdec(gmax[0]) + ad4.x);
    const float M1 = lrelu(fdec(gmax[1]) + ad4.y);
    const float M2 = lrelu(fdec(gmax[2]) + ad4.z);
    const float M3 = lrelu(fdec(gmax[3]) + ad4.w);

    // self loop
    const float q0 = __expf(lrelu(as4.x + ad4.x) - M0);
    const float q1 = __expf(lrelu(as4.y + ad4.y) - M1);
    const float q2 = __expf(lrelu(as4.z + ad4.z) - M2);
    const float q3 = __expf(lrelu(as4.w + ad4.w) - M3);
    float s0 = q0, s1 = q1, s2 = q2, s3 = q3;
    const uint2 hs = *(const uint2*)(hB + ((size_t)node << 8) + f8);
    float a0 = q0 * bflo(hs.x);   // pos0 = head0
    float a1 = q1 * bfhi(hs.x);   // pos1 = head2
    float a2 = q2 * bflo(hs.y);   // pos2 = head1
    float a3 = q3 * bfhi(hs.y);   // pos3 = head3

    int i = beg;
    for (; i + 8 <= end; i += 8) {
        u32x4 e[8];
#pragma unroll
        for (int u = 0; u < 8; ++u)
            e[u] = __builtin_nontemporal_load(&eB[i + u]);  // {s16,d16,q01,q23}
        uint2 h[8];
#pragma unroll
        for (int u = 0; u < 8; ++u)
            h[u] = *(const uint2*)(hB + (((unsigned)e[u].x) << 4) + f8);
#pragma unroll
        for (int u = 0; u < 8; ++u) {
            const float2 qa = unpack_h2(e[u].z);
            const float2 qb = unpack_h2(e[u].w);
            s0 += qa.x; s1 += qa.y; s2 += qb.x; s3 += qb.y;
            a0 = fmaf(qa.x, bflo(h[u].x), a0);
            a1 = fmaf(qa.y, bfhi(h[u].x), a1);
            a2 = fmaf(qb.x, bflo(h[u].y), a2);
            a3 = fmaf(qb.y, bfhi(h[u].y), a3);
        }
    }
    for (; i < end; ++i) {
        const u32x4 e = __builtin_nontemporal_load(&eB[i]);
        const uint2 h = *(const uint2*)(hB + (((unsigned)e.x) << 4) + f8);
        const float2 qa = unpack_h2(e.z);
        const float2 qb = unpack_h2(e.w);
        s0 += qa.x; s1 += qa.y; s2 += qb.x; s3 += qb.y;
        a0 = fmaf(qa.x, bflo(h.x), a0);
        a1 = fmaf(qa.y, bfhi(h.x), a1);
        a2 = fmaf(qb.x, bflo(h.y), a2);
        a3 = fmaf(qb.y, bfhi(h.y), a3);
    }

    float v = a0 / s0 + a1 / s1 + a2 / s2 + a3 / s3;
    v = v * 0.25f + bias[f];
    if (apply_elu) v = (v > 0.f) ? v : (__expf(v) - 1.f);
    outp[(size_t)node * 32 + f] = v;
}

// ---------------- launch ----------------

extern "C" void kernel_launch(void* const* d_in, const int* in_sizes, int n_in,
                              void* d_out, int out_size, void* d_ws, size_t ws_size,
                              hipStream_t stream) {
    const int N = in_sizes[0] / 128;
    const int E = in_sizes[1] / 2;
    const float* x = (const float*)d_in[0];
    const int* ei = (const int*)d_in[1];
    const float* W1 = (const float*)d_in[2];
    const float* atS1 = (const float*)d_in[3];
    const float* atD1 = (const float*)d_in[4];
    const float* b1 = (const float*)d_in[5];
    const float* W2 = (const float*)d_in[6];
    const float* atS2 = (const float*)d_in[7];
    const float* atD2 = (const float*)d_in[8];
    const float* b2 = (const float*)d_in[9];
    float* out = (float*)d_out;

    char* ws = (char*)d_ws;
    size_t off = 0;
    auto alloc = [&](size_t bytes) {
        void* p = ws + off;
        off = (off + bytes + 255) & ~(size_t)255;
        return p;
    };
    unsigned int* gmax = (unsigned int*)alloc(8 * sizeof(unsigned int)); // [layer][pos]
    unsigned short* cnt_priv = (unsigned short*)alloc((size_t)NS * N * 2);
    int* deg = (int*)alloc((size_t)N * 4);
    int* rowptr = (int*)alloc((size_t)(N + 1) * 4);
    int* bsum = (int*)alloc(256 * 4);
    int* boff = (int*)alloc(256 * 4);
    uint4* esd = (uint4*)alloc((size_t)E * 16);
    unsigned short* hb = (unsigned short*)alloc((size_t)N * 128 * 2);  // packed bf16
    float* av_s = (float*)alloc((size_t)N * 4 * 4);
    float* av_d = (float*)alloc((size_t)N * 4 * 4);
    float* x2 = (float*)alloc((size_t)N * 32 * 4);

    const int* e_src = ei;
    const int* e_dst = ei + E;

    const int gemmGrid = (N + 63) / 64;
    const int nodeGrid = (N + 7) / 8;
    const int npbS = (N + NB_S - 1) / NB_S;  // scatter bucket size
    const int npbH = (N + NB_H - 1) / NB_H;  // hist bucket size
    const int scanGrid = (N + 255) / 256;    // must be <= 256
    const int scatGrid = NB_S * NS;
    const int histGrid = NB_H * NS;

    (void)hipMemsetAsync(gmax, 0, 8 * sizeof(unsigned int), stream);

    // layer-1 GEMM + hist fused (independent work, one dispatch)
    gemm_hist<128><<<gemmGrid + histGrid, 256, 0, stream>>>(
        x, W1, atS1, atD1, hb, av_s, av_d, gmax, N, gemmGrid,
        e_dst, cnt_priv, E, npbH);
    scan_part<<<scanGrid, 256, 0, stream>>>(cnt_priv, deg, bsum, N);
    scan_mid<<<1, 256, 0, stream>>>(bsum, boff, scanGrid, rowptr, N);
    scan_final<<<scanGrid, 256, 0, stream>>>(deg, boff, rowptr, N);
    scatter_kernel<<<scatGrid, 512, 0, stream>>>(
        e_src, e_dst, rowptr, cnt_priv, av_s, av_d, gmax, esd, E, N, npbS);
    node_kernel<<<nodeGrid, 256, 0, stream>>>(rowptr, esd, hb, av_s, av_d, gmax,
                                              b1, x2, N, 1);
    // layer 2
    gemm_hist<32><<<gemmGrid, 256, 0, stream>>>(
        x2, W2, atS2, atD2, hb, av_s, av_d, gmax + 4, N, gemmGrid,
        nullptr, nullptr, 0, 0);
    edge_w_kernel<<<2048, 256, 0, stream>>>(esd, av_s, av_d, gmax + 4, E);
    node_kernel<<<nodeGrid, 256, 0, stream>>>(rowptr, esd, hb, av_s, av_d, gmax + 4,
                                              b2, out, N, 0);
}